// Round 6
// baseline (222.392 us; speedup 1.0000x reference)
//
#include <hip/hip_runtime.h>
#include <hip/hip_bf16.h>
#include <math.h>

#define B_   4
#define C_   256
#define H_   56
#define W_   56
#define HW_  3136
#define OC1  128
#define NT   49
#define HP_  68          // 56 + 2*6 padded
#define M_TOT 12544      // B_*HW_

typedef __attribute__((ext_vector_type(8))) short bf16x8;
typedef __attribute__((ext_vector_type(4))) float f32x4;

// ===========================================================================
// FAST PATH: bf16 MFMA implicit GEMM for conv1, cc-blocked xp layout
// xp2 layout: [cc 8][b 4][hp 68][wp 68][ci 32] bf16
// ===========================================================================

// Pack x (f32 NCHW) -> xp2, zero borders. One block per (cc, b, hp).
__global__ __launch_bounds__(256) void xpack2_kernel(const float* __restrict__ x,
                                                     __hip_bfloat16* __restrict__ xp)
{
    __shared__ short tile[HP_ * 32];     // [wp][ci]
    int bid = blockIdx.x;                // < 8*4*68 = 2176
    int cc = bid / (B_ * HP_);
    int r  = bid - cc * (B_ * HP_);
    int b  = r / HP_;
    int hp = r - b * HP_;
    int h  = hp - 6;
    int tid = threadIdx.x;

    if (h < 0 || h >= H_) {
        for (int idx = tid; idx < HP_ * 32; idx += 256) tile[idx] = 0;
    } else {
        int ci = tid >> 3;               // 0..31
        int wg = tid & 7;                // 0..7
        const float* xr = x + ((size_t)(b * C_ + cc * 32 + ci) * H_ + h) * W_;
        #pragma unroll
        for (int k = 0; k < 7; ++k) {
            int w = wg + 8 * k;          // covers 0..55 exactly
            __hip_bfloat16 v = __float2bfloat16(xr[w]);
            tile[(w + 6) * 32 + ci] = *(short*)&v;
        }
        // zero left/right borders: wp in [0,6) and [62,68): 12*32 = 384 entries
        for (int idx = tid; idx < 384; idx += 256) {
            int wp = idx >> 5;           // 0..11
            int wz = (wp < 6) ? wp : (wp + 56);
            tile[wz * 32 + (idx & 31)] = 0;
        }
    }
    __syncthreads();
    // contiguous write: 68*32 = 2176 shorts = 272 x 16B
    short* outp = (short*)xp + ((size_t)((cc * B_ + b) * HP_ + hp) * HP_) * 32;
    for (int idx = tid; idx < 272; idx += 256)
        *(bf16x8*)(outp + idx * 8) = *(bf16x8*)(tile + idx * 8);
}

// Pack W1 -> wTb2 bf16 fragment order: [tap49][cc8][ntile8][lane64][j8]
// lane: n = ntile*16 + (lane&15); k(c) = cc*32 + (lane>>4)*8 + j   (validated R3)
__global__ __launch_bounds__(256) void wpack_kernel(const float* __restrict__ W1,
                                                    __hip_bfloat16* __restrict__ wTb2)
{
    int idx = blockIdx.x * 256 + threadIdx.x;      // < 49*8*8*64*8 = 1,605,632
    int j8    = idx & 7;
    int l     = (idx >> 3) & 63;
    int ntile = (idx >> 9) & 7;
    int cc    = (idx >> 12) & 7;
    int tap   = idx >> 15;                          // 0..48
    int n = ntile * 16 + (l & 15);
    int c = cc * 32 + (l >> 4) * 8 + j8;
    wTb2[idx] = __float2bfloat16(W1[((size_t)n * C_ + c) * NT + tap]);
}

// conv1 implicit GEMM. R6: flat 56-step K-loop, fully unrolled, with
// register double-buffered fragments (prefetch it+1 while MFMA on it) —
// attacks the 22% MfmaUtil load-stall serialization seen in R5's profile.
// Index math and MFMA/store logic identical to validated R4/R5 kernel.
__global__ __launch_bounds__(256) void conv1_mfma2(const __hip_bfloat16* __restrict__ xp,
                                                   const __hip_bfloat16* __restrict__ wTb2,
                                                   float* __restrict__ kpart)
{
    const int bid = blockIdx.x;
    const int g   = bid & 7;              // presumed XCD (round-robin dispatch)
    const int kk  = bid >> 3;             // 0..90
    const int s   = (g * 98) >> 3;
    const int cnt = (((g + 1) * 98) >> 3) - s;   // 12 or 13
    const int i   = kk / cnt;             // tap row
    if (i >= 7) return;
    const int mblk = s + (kk - i * cnt);
    const int m0   = mblk * 128;

    const int tid  = threadIdx.x;
    const int lane = tid & 63;
    const int wid  = tid >> 6;
    const int waveM = wid >> 1, waveN = wid & 1;
    const int quad = lane >> 4, l16 = lane & 15;

    const short* xps = (const short*)xp;
    const short* wbs = (const short*)wTb2;
    const long CC_STRIDE = (long)B_ * HP_ * HP_ * 32;   // 591,872 elements

    long abase[4];
    #pragma unroll
    for (int mt = 0; mt < 4; ++mt) {
        int m = m0 + waveM * 64 + mt * 16 + l16;
        int b = m / HW_; int hw = m - b * HW_;
        int h = hw / W_; int w = hw - h * W_;
        abase[mt] = ((long)(b * HP_ + (h + 2 * i)) * HP_ + w) * 32 + quad * 8;
    }

    f32x4 acc[4][4];
    #pragma unroll
    for (int a = 0; a < 4; ++a)
        #pragma unroll
        for (int b2 = 0; b2 < 4; ++b2) acc[a][b2] = (f32x4){0.f, 0.f, 0.f, 0.f};

    const long bwave = (long)(waveN * 4) * 512 + lane * 8;
    const long btap  = (long)i * 7 * 32768;

    // ping-pong fragment buffers; flat it = cc*7 + j, fully unrolled so
    // buffer indices and cc/j divisions fold to constants.
    bf16x8 af[2][4], bfr[2][4];

    // preload it=0 (cc=0, j=0)
    #pragma unroll
    for (int mt = 0; mt < 4; ++mt)
        af[0][mt] = *(const bf16x8*)(xps + abase[mt]);
    #pragma unroll
    for (int nt = 0; nt < 4; ++nt)
        bfr[0][nt] = *(const bf16x8*)(wbs + btap + (long)nt * 512 + bwave);

    #pragma unroll
    for (int it = 0; it < 56; ++it) {
        const int cur = it & 1, nxt = cur ^ 1;
        if (it < 55) {
            const int cc = (it + 1) / 7;       // compile-time after unroll
            const int j  = (it + 1) % 7;
            const long aoffj = (long)cc * CC_STRIDE + (long)j * 64;
            const long boffj = btap + (long)j * 32768 + (long)cc * 4096;
            #pragma unroll
            for (int mt = 0; mt < 4; ++mt)
                af[nxt][mt] = *(const bf16x8*)(xps + abase[mt] + aoffj);
            #pragma unroll
            for (int nt = 0; nt < 4; ++nt)
                bfr[nxt][nt] = *(const bf16x8*)(wbs + boffj + (long)nt * 512 + bwave);
        }
        #pragma unroll
        for (int mt = 0; mt < 4; ++mt)
            #pragma unroll
            for (int nt = 0; nt < 4; ++nt)
                acc[mt][nt] = __builtin_amdgcn_mfma_f32_16x16x32_bf16(
                    af[cur][mt], bfr[cur][nt], acc[mt][nt], 0, 0, 0);
    }

    // Store: C/D layout col(n)=lane&15, row(m)=quad*4+reg  (validated R3)
    #pragma unroll
    for (int mt = 0; mt < 4; ++mt) {
        int mrow = m0 + waveM * 64 + mt * 16 + quad * 4;
        #pragma unroll
        for (int nt = 0; nt < 4; ++nt) {
            int n = waveN * 64 + nt * 16 + l16;
            float* dst = kpart + ((long)i * M_TOT + mrow) * OC1 + n;
            #pragma unroll
            for (int r = 0; r < 4; ++r)
                dst[(long)r * OC1] = acc[mt][nt][r];
        }
    }
}

// conv2 + b2 + softmax, folding 7 kpart slices + b1 (validated R4).
__global__ __launch_bounds__(256) void attn_kernel3(const float* __restrict__ kpart,
                                                    const float* __restrict__ b1,
                                                    const float* __restrict__ W2,
                                                    const float* __restrict__ b2,
                                                    float* __restrict__ attn)
{
    __shared__ float ksum[128 * 33];     // [c][pix], pad 33
    __shared__ float sW2[128 * 49];      // [c][l]
    __shared__ float sredA[32 * 8];
    __shared__ float sredB[32 * 8];

    int tid  = threadIdx.x;
    int pix0 = blockIdx.x * 32;

    for (int idx = tid; idx < 128 * 49; idx += 256) {
        int c = idx / 49, l = idx - c * 49;
        sW2[idx] = W2[l * 128 + c];
    }

    int pix = tid >> 3, cg = tid & 7;
    {
        const float* kp = kpart + (size_t)(pix0 + pix) * OC1;
        #pragma unroll
        for (int q = 0; q < 4; ++q) {
            int c4 = cg * 16 + q * 4;
            float4 s = *(const float4*)(b1 + c4);
            #pragma unroll
            for (int sp = 0; sp < 7; ++sp) {
                float4 p = *(const float4*)(kp + (size_t)sp * M_TOT * OC1 + c4);
                s.x += p.x; s.y += p.y; s.z += p.z; s.w += p.w;
            }
            ksum[(c4 + 0) * 33 + pix] = s.x;
            ksum[(c4 + 1) * 33 + pix] = s.y;
            ksum[(c4 + 2) * 33 + pix] = s.z;
            ksum[(c4 + 3) * 33 + pix] = s.w;
        }
    }
    __syncthreads();

    int sub = tid & 7;
    float lg[7];
    int ntaps = 0;
    float lmax = -INFINITY;
    for (int l = sub; l < 49; l += 8) {
        float acc = b2[l];
        #pragma unroll 8
        for (int c = 0; c < 128; ++c)
            acc += ksum[c * 33 + pix] * sW2[c * 49 + l];
        lg[ntaps++] = acc;
        lmax = fmaxf(lmax, acc);
    }
    sredA[pix * 8 + sub] = lmax;
    __syncthreads();

    float m = sredA[pix * 8 + 0];
    #pragma unroll
    for (int t = 1; t < 8; ++t) m = fmaxf(m, sredA[pix * 8 + t]);
    float es = 0.f;
    for (int t = 0; t < ntaps; ++t) { lg[t] = __expf(lg[t] - m); es += lg[t]; }
    sredB[pix * 8 + sub] = es;
    __syncthreads();

    float S = 0.f;
    #pragma unroll
    for (int t = 0; t < 8; ++t) S += sredB[pix * 8 + t];
    float rinv = 1.0f / S;

    int pg = pix0 + pix;
    int b  = pg / HW_;
    int hw = pg - b * HW_;
    int t = 0;
    for (int l = sub; l < 49; l += 8, ++t)
        attn[((size_t)b * NT + l) * HW_ + hw] = lg[t] * rinv;
}

// out[b,c,h,w] = sum_ij attn[b,ij,h,w] * x[b,c,ih,iw]   (validated R5)
__global__ __launch_bounds__(256) void out_kernel3(const float* __restrict__ x,
                                                   const float* __restrict__ attn,
                                                   float* __restrict__ out)
{
    __shared__ float sX[7 * HP_ * 16];   // [i][wp][c] = 7616 floats, 30.5 KB
    __shared__ float sA[NT * 56];        // [tap][w], 11 KB

    int bid = blockIdx.x;                // < 3584
    int g   = bid & 7;                   // presumed XCD
    int s   = bid >> 3;                  // 0..447
    int bh  = g * 28 + (s % 28);         // 28 bh-rows per XCD slot
    int cg  = s / 28;                    // 0..15
    int b   = bh / H_;
    int h   = bh - b * H_;
    int c0  = cg * 16;
    int tid = threadIdx.x;

    for (int idx = tid; idx < 7 * HP_ * 16; idx += 256)
        sX[idx] = 0.0f;
    __syncthreads();

    for (int idx = tid; idx < NT * 56; idx += 256) {
        int l = idx / 56, w = idx - l * 56;
        sA[idx] = attn[((size_t)b * NT + l) * HW_ + h * W_ + w];
    }
    {
        int c  = tid >> 4;
        int wg = tid & 15;
        const float* xc = x + (size_t)(b * C_ + c0 + c) * HW_;
        #pragma unroll
        for (int i = 0; i < 7; ++i) {
            int ih = h + 2 * i - 6;
            if (ih < 0 || ih >= H_) continue;
            const float* xr = xc + ih * W_;
            #pragma unroll
            for (int k = 0; k < 4; ++k) {
                int w = wg + 16 * k;
                if (w < W_)
                    sX[(i * HP_ + (w + 6)) * 16 + c] = xr[w];
            }
        }
    }
    __syncthreads();

    int lane = tid & 63;
    int wid  = tid >> 6;                 // wave -> channels c0+wid*4 .. +3
    int w    = lane;
    bool active = (w < W_);
    int wc = active ? w : (W_ - 1);

    float aR[NT];
    #pragma unroll
    for (int l = 0; l < NT; ++l)
        aR[l] = sA[l * 56 + wc];

    f32x4 acc = (f32x4){0.f, 0.f, 0.f, 0.f};
    #pragma unroll
    for (int i = 0; i < 7; ++i) {
        #pragma unroll
        for (int j = 0; j < 7; ++j) {
            f32x4 xv = *(const f32x4*)&sX[(i * HP_ + (wc + 2 * j)) * 16 + wid * 4];
            float a = aR[i * 7 + j];
            acc.x += a * xv.x; acc.y += a * xv.y;
            acc.z += a * xv.z; acc.w += a * xv.w;
        }
    }

    if (active) {
        size_t o = ((size_t)(b * C_ + c0 + wid * 4)) * HW_ + h * W_ + w;
        out[o + 0 * HW_] = acc.x;
        out[o + 1 * HW_] = acc.y;
        out[o + 2 * HW_] = acc.z;
        out[o + 3 * HW_] = acc.w;
    }
}

// ===========================================================================
// FALLBACK PATH (R1, proven): used only if ws_size < fast-path need
// ===========================================================================
__global__ __launch_bounds__(256) void wt_kernel(const float* __restrict__ W1,
                                                 float* __restrict__ wT)
{
    int idx = blockIdx.x * 256 + threadIdx.x;
    int oc = idx & 127;
    int ct = idx >> 7;
    wT[idx] = W1[oc * (C_ * NT) + ct];
}

__global__ __launch_bounds__(256) void conv1_kernel(const float* __restrict__ x,
                                                    const float* __restrict__ wT,
                                                    const float* __restrict__ b1,
                                                    float* __restrict__ k)
{
    int tid = threadIdx.x;
    int w   = tid & 63;
    int ty  = tid >> 6;
    int h   = blockIdx.x * 4 + ty;
    int oc0 = blockIdx.y * 8;
    int b   = blockIdx.z;

    const float* xb = x + (size_t)b * C_ * HW_;
    float acc[8] = {0.f,0.f,0.f,0.f,0.f,0.f,0.f,0.f};

    for (int i = 0; i < 7; ++i) {
        int ih = h + 2 * i - 6;
        if (ih < 0 || ih >= H_) continue;
        for (int j = 0; j < 7; ++j) {
            int iw = w + 2 * j - 6;
            bool v  = (iw >= 0) && (iw < W_);
            float m = v ? 1.0f : 0.0f;
            const float* xr = xb + ih * W_ + (v ? iw : 0);
            const float* wr = wT + (size_t)(i * 7 + j) * OC1 + oc0;
            #pragma unroll 4
            for (int c = 0; c < C_; ++c) {
                float xv = m * xr[(size_t)c * HW_];
                const float4 w0 = *(const float4*)(wr + (size_t)c * NT * OC1);
                const float4 w1 = *(const float4*)(wr + (size_t)c * NT * OC1 + 4);
                acc[0] += xv * w0.x; acc[1] += xv * w0.y;
                acc[2] += xv * w0.z; acc[3] += xv * w0.w;
                acc[4] += xv * w1.x; acc[5] += xv * w1.y;
                acc[6] += xv * w1.z; acc[7] += xv * w1.w;
            }
        }
    }
    if (w < W_) {
        size_t o = ((size_t)(b * OC1 + oc0)) * HW_ + h * W_ + w;
        #pragma unroll
        for (int q = 0; q < 8; ++q)
            k[o + (size_t)q * HW_] = acc[q] + b1[oc0 + q];
    }
}

__global__ __launch_bounds__(256) void attn_kernel(const float* __restrict__ kin,
                                                   const float* __restrict__ W2,
                                                   const float* __restrict__ b2,
                                                   float* __restrict__ attn)
{
    __shared__ float sW2[128 * 49];
    int tid = threadIdx.x;
    for (int idx = tid; idx < 128 * 49; idx += 256) {
        int c = idx / 49, l = idx - c * 49;
        sW2[idx] = W2[l * 128 + c];
    }
    __syncthreads();

    int wid  = tid >> 6;
    int lane = tid & 63;
    int pix  = blockIdx.x * 4 + wid;
    int b    = pix / HW_;
    int hw   = pix - b * HW_;
    int l    = (lane < 49) ? lane : 0;

    const float* kb = kin + (size_t)b * OC1 * HW_ + hw;
    float acc = b2[l];
    #pragma unroll 8
    for (int c = 0; c < 128; ++c)
        acc += kb[(size_t)c * HW_] * sW2[c * 49 + l];

    float logit = (lane < 49) ? acc : -INFINITY;
    float mx = logit;
    for (int s = 32; s > 0; s >>= 1) mx = fmaxf(mx, __shfl_xor(mx, s, 64));
    float e = (lane < 49) ? __expf(logit - mx) : 0.0f;
    float sum = e;
    for (int s = 32; s > 0; s >>= 1) sum += __shfl_xor(sum, s, 64);
    if (lane < 49)
        attn[((size_t)b * NT + lane) * HW_ + hw] = e / sum;
}

__global__ __launch_bounds__(256) void out_kernel(const float* __restrict__ x,
                                                  const float* __restrict__ attn,
                                                  float* __restrict__ out)
{
    int idx = blockIdx.x * 256 + threadIdx.x;
    int w  = idx % 56;
    int t  = idx / 56;
    int h  = t % 56;
    int t2 = t / 56;
    int c  = t2 & 255;
    int b  = t2 >> 8;

    const float* xb = x + (size_t)(b * C_ + c) * HW_;
    const float* ab = attn + (size_t)b * NT * HW_ + h * W_ + w;

    float acc = 0.f;
    #pragma unroll
    for (int i = 0; i < 7; ++i) {
        int ih = h + 2 * i - 6;
        bool hv = (ih >= 0) && (ih < H_);
        #pragma unroll
        for (int j = 0; j < 7; ++j) {
            int iw = w + 2 * j - 6;
            bool v  = hv && (iw >= 0) && (iw < W_);
            float m = v ? 1.0f : 0.0f;
            int off = v ? (ih * W_ + iw) : 0;
            acc += (m * xb[off]) * ab[(size_t)(i * 7 + j) * HW_];
        }
    }
    out[idx] = acc;
}

// ===========================================================================
extern "C" void kernel_launch(void* const* d_in, const int* in_sizes, int n_in,
                              void* d_out, int out_size, void* d_ws, size_t ws_size,
                              hipStream_t stream)
{
    const float* x  = (const float*)d_in[0];
    const float* W1 = (const float*)d_in[1];
    const float* b1 = (const float*)d_in[2];
    const float* W2 = (const float*)d_in[3];
    const float* b2 = (const float*)d_in[4];
    float* out = (float*)d_out;

    const size_t xp_b    = (size_t)B_ * HP_ * HP_ * 256 * 2;        //  9,469,952
    const size_t wtb_b   = (size_t)NT * 8 * 8 * 64 * 8 * 2;         //  3,211,264
    const size_t kpart_b = (size_t)7 * M_TOT * OC1 * 4;             // 44,957,696
    const size_t attn_b  = (size_t)B_ * NT * HW_ * 4;               //  2,458,624
    const size_t need = xp_b + wtb_b + kpart_b + attn_b;            // 60,097,536

    if (ws_size >= need) {
        char* base = (char*)d_ws;
        __hip_bfloat16* xp   = (__hip_bfloat16*)base;
        __hip_bfloat16* wTb2 = (__hip_bfloat16*)(base + xp_b);
        float* kpart = (float*)(base + xp_b + wtb_b);
        float* attn  = (float*)(base + xp_b + wtb_b + kpart_b);

        xpack2_kernel<<<2176, 256, 0, stream>>>(x, xp);
        wpack_kernel <<<6272, 256, 0, stream>>>(W1, wTb2);
        conv1_mfma2  <<<728, 256, 0, stream>>>(xp, wTb2, kpart);
        attn_kernel3 <<<392, 256, 0, stream>>>(kpart, b1, W2, b2, attn);
        out_kernel3  <<<3584, 256, 0, stream>>>(x, attn, out);
    } else {
        // R1 fallback (~14.6 MB)
        float* wT   = (float*)d_ws;
        float* kbuf = wT + 1605632;
        float* attn = kbuf + 1605632;
        wt_kernel   <<<6272, 256, 0, stream>>>(W1, wT);
        conv1_kernel<<<dim3(14, 16, 4), 256, 0, stream>>>(x, wT, b1, kbuf);
        attn_kernel <<<3136, 256, 0, stream>>>(kbuf, W2, b2, attn);
        out_kernel  <<<12544, 256, 0, stream>>>(x, attn, out);
    }
}

// Round 7
// 204.077 us; speedup vs baseline: 1.0897x; 1.0897x over previous
//
#include <hip/hip_runtime.h>
#include <hip/hip_bf16.h>
#include <math.h>

#define B_   4
#define C_   256
#define H_   56
#define W_   56
#define HW_  3136
#define OC1  128
#define NT   49
#define NP   64          // padded logit count
#define HP_  68          // 56 + 2*6 padded
#define M_TOT 12544      // B_*HW_

typedef __attribute__((ext_vector_type(8))) short bf16x8;
typedef __attribute__((ext_vector_type(4))) float f32x4;

// ===========================================================================
// FAST PATH: fused-weight bf16 MFMA implicit GEMM (conv2 folded into conv1)
// logits = conv(x, Wf) + cb,  Wf[l,c,tap] = sum_oc W2[l,oc]*W1[oc,c,tap]
// xp2 layout: [cc 8][b 4][hp 68][wp 68][ci 32] bf16   (validated R4-R6)
// wfb layout: [tap 49][cc 8][ntile 4][lane 64][j 8] bf16 fragment order
// ===========================================================================

// Pack x (f32 NCHW) -> xp2, zero borders. One block per (cc, b, hp). (validated)
__global__ __launch_bounds__(256) void xpack2_kernel(const float* __restrict__ x,
                                                     __hip_bfloat16* __restrict__ xp)
{
    __shared__ short tile[HP_ * 32];     // [wp][ci]
    int bid = blockIdx.x;                // < 8*4*68 = 2176
    int cc = bid / (B_ * HP_);
    int r  = bid - cc * (B_ * HP_);
    int b  = r / HP_;
    int hp = r - b * HP_;
    int h  = hp - 6;
    int tid = threadIdx.x;

    if (h < 0 || h >= H_) {
        for (int idx = tid; idx < HP_ * 32; idx += 256) tile[idx] = 0;
    } else {
        int ci = tid >> 3;               // 0..31
        int wg = tid & 7;                // 0..7
        const float* xr = x + ((size_t)(b * C_ + cc * 32 + ci) * H_ + h) * W_;
        #pragma unroll
        for (int k = 0; k < 7; ++k) {
            int w = wg + 8 * k;          // covers 0..55 exactly
            __hip_bfloat16 v = __float2bfloat16(xr[w]);
            tile[(w + 6) * 32 + ci] = *(short*)&v;
        }
        for (int idx = tid; idx < 384; idx += 256) {
            int wp = idx >> 5;           // 0..11
            int wz = (wp < 6) ? wp : (wp + 56);
            tile[wz * 32 + (idx & 31)] = 0;
        }
    }
    __syncthreads();
    short* outp = (short*)xp + ((size_t)((cc * B_ + b) * HP_ + hp) * HP_) * 32;
    for (int idx = tid; idx < 272; idx += 256)
        *(bf16x8*)(outp + idx * 8) = *(bf16x8*)(tile + idx * 8);
}

// Fused-weight pack: Wf -> fragment order [tap][cc][ntile4][lane][j8].
// n = ntile*16 + (l&15) (0 for n>=49); c = cc*32 + (l>>4)*8 + j  (same
// lane->element mapping as the validated R3 wpack, just ntile4 wide).
// One block per (tap, cc).
__global__ __launch_bounds__(256) void wfuse_kernel(const float* __restrict__ W1,
                                                    const float* __restrict__ W2,
                                                    __hip_bfloat16* __restrict__ wfb)
{
    __shared__ float sW2[NP * 129];      // [n][oc], stride 129 kills bank conflicts
    __shared__ float sW1[128 * 32];      // [oc][ci]
    int tap = blockIdx.x;                // 0..48
    int cc  = blockIdx.y;                // 0..7
    int tid = threadIdx.x;

    for (int idx = tid; idx < NP * 128; idx += 256) {
        int n = idx >> 7, oc = idx & 127;
        sW2[n * 129 + oc] = (n < NT) ? W2[n * 128 + oc] : 0.0f;
    }
    for (int idx = tid; idx < 128 * 32; idx += 256) {
        int oc = idx >> 5, ci = idx & 31;
        sW1[idx] = W1[((size_t)(oc * C_ + cc * 32 + ci)) * NT + tap];
    }
    __syncthreads();

    int ntile = tid >> 6;
    int l     = tid & 63;
    int n     = ntile * 16 + (l & 15);
    int q     = l >> 4;

    float acc[8] = {0,0,0,0,0,0,0,0};
    for (int oc = 0; oc < 128; ++oc) {
        float w2 = sW2[n * 129 + oc];
        const float* r = &sW1[oc * 32 + q * 8];
        #pragma unroll
        for (int j = 0; j < 8; ++j)
            acc[j] += w2 * r[j];
    }

    short pk[8];
    #pragma unroll
    for (int j = 0; j < 8; ++j) {
        __hip_bfloat16 v = __float2bfloat16(acc[j]);
        pk[j] = *(short*)&v;
    }
    short* dst = (short*)wfb + ((size_t)(tap * 8 + cc) * 4 + ntile) * 512 + l * 8;
    *(bf16x8*)dst = *(bf16x8*)pk;
}

// cb[l] = b2[l] + sum_oc W2[l,oc]*b1[oc]  (one wave)
__global__ __launch_bounds__(64) void cbias_kernel(const float* __restrict__ W2,
                                                   const float* __restrict__ b1,
                                                   const float* __restrict__ b2,
                                                   float* __restrict__ cb)
{
    int l = threadIdx.x;
    float a = 0.0f;
    if (l < NT) {
        a = b2[l];
        for (int oc = 0; oc < 128; ++oc)
            a += W2[l * 128 + oc] * b1[oc];
    }
    cb[l] = a;
}

// Fused conv implicit GEMM: M=12544, N=64(49), K=1792 per tap-row i.
// Same grid/swizzle/A-indexing/loop as validated R5 conv1_mfma2; only the
// B side narrows (ntile4) and the store width drops to 64.
__global__ __launch_bounds__(256) void conv1_mfma3(const __hip_bfloat16* __restrict__ xp,
                                                   const __hip_bfloat16* __restrict__ wfb,
                                                   float* __restrict__ kpart)
{
    const int bid = blockIdx.x;
    const int g   = bid & 7;              // presumed XCD (round-robin dispatch)
    const int kk  = bid >> 3;             // 0..90
    const int s   = (g * 98) >> 3;
    const int cnt = (((g + 1) * 98) >> 3) - s;   // 12 or 13
    const int i   = kk / cnt;             // tap row
    if (i >= 7) return;
    const int mblk = s + (kk - i * cnt);
    const int m0   = mblk * 128;

    const int tid  = threadIdx.x;
    const int lane = tid & 63;
    const int wid  = tid >> 6;
    const int waveM = wid >> 1, waveN = wid & 1;
    const int quad = lane >> 4, l16 = lane & 15;

    const short* xps = (const short*)xp;
    const short* wbs = (const short*)wfb;
    const long CC_STRIDE = (long)B_ * HP_ * HP_ * 32;   // 591,872 elements

    long abase[4];
    #pragma unroll
    for (int mt = 0; mt < 4; ++mt) {
        int m = m0 + waveM * 64 + mt * 16 + l16;
        int b = m / HW_; int hw = m - b * HW_;
        int h = hw / W_; int w = hw - h * W_;
        abase[mt] = ((long)(b * HP_ + (h + 2 * i)) * HP_ + w) * 32 + quad * 8;
    }

    f32x4 acc[4][2];
    #pragma unroll
    for (int a = 0; a < 4; ++a)
        #pragma unroll
        for (int b2 = 0; b2 < 2; ++b2) acc[a][b2] = (f32x4){0.f, 0.f, 0.f, 0.f};

    const long bwave = (long)waveN * 1024 + lane * 8;   // waveN picks ntile pair

    #pragma unroll
    for (int cc = 0; cc < 8; ++cc) {
        const long aoffc = (long)cc * CC_STRIDE;
        const long boffc = (long)cc * 2048;
        for (int j = 0; j < 7; ++j) {
            const long aoffj = aoffc + (long)j * 64;              // wp += 2
            const long boffj = (long)(i * 7 + j) * 16384 + boffc; // tap*8cc*4nt*512
            bf16x8 af[4], bfr[2];
            #pragma unroll
            for (int mt = 0; mt < 4; ++mt)
                af[mt] = *(const bf16x8*)(xps + abase[mt] + aoffj);
            #pragma unroll
            for (int nt = 0; nt < 2; ++nt)
                bfr[nt] = *(const bf16x8*)(wbs + boffj + (long)nt * 512 + bwave);
            #pragma unroll
            for (int mt = 0; mt < 4; ++mt)
                #pragma unroll
                for (int nt = 0; nt < 2; ++nt)
                    acc[mt][nt] = __builtin_amdgcn_mfma_f32_16x16x32_bf16(
                        af[mt], bfr[nt], acc[mt][nt], 0, 0, 0);
        }
    }

    // Store: C/D layout col(n)=lane&15, row(m)=quad*4+reg (validated)
    #pragma unroll
    for (int mt = 0; mt < 4; ++mt) {
        int mrow = m0 + waveM * 64 + mt * 16 + quad * 4;
        #pragma unroll
        for (int nt = 0; nt < 2; ++nt) {
            int n = waveN * 32 + nt * 16 + l16;
            float* dst = kpart + ((long)i * M_TOT + mrow) * NP + n;
            #pragma unroll
            for (int r = 0; r < 4; ++r)
                dst[(long)r * NP] = acc[mt][nt][r];
        }
    }
}

// Fold 7 partial-logit slices + cb, softmax over 49, write pixel-major attnP.
// One wave per pixel; lane = logit. Fully coalesced reads (64x4B) and writes.
__global__ __launch_bounds__(256) void attn_fold(const float* __restrict__ kpart,
                                                 const float* __restrict__ cb,
                                                 float* __restrict__ attnP)
{
    int tid  = threadIdx.x;
    int wid  = tid >> 6;
    int lane = tid & 63;
    int pix  = blockIdx.x * 4 + wid;     // < 12544

    const float* kp = kpart + (size_t)pix * NP + lane;
    float v = 0.0f;
    #pragma unroll
    for (int sp = 0; sp < 7; ++sp)
        v += kp[(size_t)sp * M_TOT * NP];

    float logit = (lane < NT) ? (v + cb[lane]) : -INFINITY;
    float mx = logit;
    for (int s = 32; s > 0; s >>= 1) mx = fmaxf(mx, __shfl_xor(mx, s, 64));
    float e = (lane < NT) ? __expf(logit - mx) : 0.0f;
    float sum = e;
    for (int s = 32; s > 0; s >>= 1) sum += __shfl_xor(sum, s, 64);
    if (lane < NT)
        attnP[(size_t)pix * NT + lane] = e / sum;
}

// Weighted 49-tap gather (R5 structure, validated) with pixel-major attnP.
// Block = (bh, 16-channel group), XCD-swizzled. sX zero-padded -> mask-free.
__global__ __launch_bounds__(256) void out_kernel4(const float* __restrict__ x,
                                                   const float* __restrict__ attnP,
                                                   float* __restrict__ out)
{
    __shared__ float sX[7 * HP_ * 16];   // [i][wp][c] 30.5 KB
    __shared__ float sA[56 * NT];        // [w][l] 10.7 KB

    int bid = blockIdx.x;                // < 3584
    int g   = bid & 7;                   // presumed XCD
    int s   = bid >> 3;                  // 0..447
    int bh  = g * 28 + (s % 28);         // 28 bh-rows per XCD slot
    int cg  = s / 28;                    // 0..15
    int b   = bh / H_;
    int h   = bh - b * H_;
    int c0  = cg * 16;
    int tid = threadIdx.x;

    for (int idx = tid; idx < 7 * HP_ * 16; idx += 256)
        sX[idx] = 0.0f;
    __syncthreads();

    // stage attn slice: contiguous [w][l] copy (fully coalesced)
    {
        const float* ap = attnP + ((size_t)(b * HW_) + h * W_) * NT;
        for (int idx = tid; idx < W_ * NT; idx += 256)
            sA[idx] = ap[idx];
    }
    // stage valid x rows
    {
        int c  = tid >> 4;
        int wg = tid & 15;
        const float* xc = x + (size_t)(b * C_ + c0 + c) * HW_;
        #pragma unroll
        for (int i = 0; i < 7; ++i) {
            int ih = h + 2 * i - 6;
            if (ih < 0 || ih >= H_) continue;
            const float* xr = xc + ih * W_;
            #pragma unroll
            for (int k = 0; k < 4; ++k) {
                int w = wg + 16 * k;
                if (w < W_)
                    sX[(i * HP_ + (w + 6)) * 16 + c] = xr[w];
            }
        }
    }
    __syncthreads();

    int lane = tid & 63;
    int wid  = tid >> 6;                 // wave -> channels c0+wid*4 .. +3
    int w    = lane;
    bool active = (w < W_);
    int wc = active ? w : (W_ - 1);

    float aR[NT];
    #pragma unroll
    for (int l = 0; l < NT; ++l)
        aR[l] = sA[wc * NT + l];

    f32x4 acc = (f32x4){0.f, 0.f, 0.f, 0.f};
    #pragma unroll
    for (int i = 0; i < 7; ++i) {
        #pragma unroll
        for (int j = 0; j < 7; ++j) {
            f32x4 xv = *(const f32x4*)&sX[(i * HP_ + (wc + 2 * j)) * 16 + wid * 4];
            float a = aR[i * 7 + j];
            acc.x += a * xv.x; acc.y += a * xv.y;
            acc.z += a * xv.z; acc.w += a * xv.w;
        }
    }

    if (active) {
        size_t o = ((size_t)(b * C_ + c0 + wid * 4)) * HW_ + h * W_ + w;
        out[o + 0 * HW_] = acc.x;
        out[o + 1 * HW_] = acc.y;
        out[o + 2 * HW_] = acc.z;
        out[o + 3 * HW_] = acc.w;
    }
}

// ===========================================================================
// FALLBACK PATH (R1, proven): used only if ws_size < fast-path need
// ===========================================================================
__global__ __launch_bounds__(256) void wt_kernel(const float* __restrict__ W1,
                                                 float* __restrict__ wT)
{
    int idx = blockIdx.x * 256 + threadIdx.x;
    int oc = idx & 127;
    int ct = idx >> 7;
    wT[idx] = W1[oc * (C_ * NT) + ct];
}

__global__ __launch_bounds__(256) void conv1_kernel(const float* __restrict__ x,
                                                    const float* __restrict__ wT,
                                                    const float* __restrict__ b1,
                                                    float* __restrict__ k)
{
    int tid = threadIdx.x;
    int w   = tid & 63;
    int ty  = tid >> 6;
    int h   = blockIdx.x * 4 + ty;
    int oc0 = blockIdx.y * 8;
    int b   = blockIdx.z;

    const float* xb = x + (size_t)b * C_ * HW_;
    float acc[8] = {0.f,0.f,0.f,0.f,0.f,0.f,0.f,0.f};

    for (int i = 0; i < 7; ++i) {
        int ih = h + 2 * i - 6;
        if (ih < 0 || ih >= H_) continue;
        for (int j = 0; j < 7; ++j) {
            int iw = w + 2 * j - 6;
            bool v  = (iw >= 0) && (iw < W_);
            float m = v ? 1.0f : 0.0f;
            const float* xr = xb + ih * W_ + (v ? iw : 0);
            const float* wr = wT + (size_t)(i * 7 + j) * OC1 + oc0;
            #pragma unroll 4
            for (int c = 0; c < C_; ++c) {
                float xv = m * xr[(size_t)c * HW_];
                const float4 w0 = *(const float4*)(wr + (size_t)c * NT * OC1);
                const float4 w1 = *(const float4*)(wr + (size_t)c * NT * OC1 + 4);
                acc[0] += xv * w0.x; acc[1] += xv * w0.y;
                acc[2] += xv * w0.z; acc[3] += xv * w0.w;
                acc[4] += xv * w1.x; acc[5] += xv * w1.y;
                acc[6] += xv * w1.z; acc[7] += xv * w1.w;
            }
        }
    }
    if (w < W_) {
        size_t o = ((size_t)(b * OC1 + oc0)) * HW_ + h * W_ + w;
        #pragma unroll
        for (int q = 0; q < 8; ++q)
            k[o + (size_t)q * HW_] = acc[q] + b1[oc0 + q];
    }
}

__global__ __launch_bounds__(256) void attn_kernel(const float* __restrict__ kin,
                                                   const float* __restrict__ W2,
                                                   const float* __restrict__ b2,
                                                   float* __restrict__ attn)
{
    __shared__ float sW2[128 * 49];
    int tid = threadIdx.x;
    for (int idx = tid; idx < 128 * 49; idx += 256) {
        int c = idx / 49, l = idx - c * 49;
        sW2[idx] = W2[l * 128 + c];
    }
    __syncthreads();

    int wid  = tid >> 6;
    int lane = tid & 63;
    int pix  = blockIdx.x * 4 + wid;
    int b    = pix / HW_;
    int hw   = pix - b * HW_;
    int l    = (lane < 49) ? lane : 0;

    const float* kb = kin + (size_t)b * OC1 * HW_ + hw;
    float acc = b2[l];
    #pragma unroll 8
    for (int c = 0; c < 128; ++c)
        acc += kb[(size_t)c * HW_] * sW2[c * 49 + l];

    float logit = (lane < 49) ? acc : -INFINITY;
    float mx = logit;
    for (int s = 32; s > 0; s >>= 1) mx = fmaxf(mx, __shfl_xor(mx, s, 64));
    float e = (lane < 49) ? __expf(logit - mx) : 0.0f;
    float sum = e;
    for (int s = 32; s > 0; s >>= 1) sum += __shfl_xor(sum, s, 64);
    if (lane < 49)
        attn[((size_t)b * NT + lane) * HW_ + hw] = e / sum;
}

__global__ __launch_bounds__(256) void out_kernel(const float* __restrict__ x,
                                                  const float* __restrict__ attn,
                                                  float* __restrict__ out)
{
    int idx = blockIdx.x * 256 + threadIdx.x;
    int w  = idx % 56;
    int t  = idx / 56;
    int h  = t % 56;
    int t2 = t / 56;
    int c  = t2 & 255;
    int b  = t2 >> 8;

    const float* xb = x + (size_t)(b * C_ + c) * HW_;
    const float* ab = attn + (size_t)b * NT * HW_ + h * W_ + w;

    float acc = 0.f;
    #pragma unroll
    for (int i = 0; i < 7; ++i) {
        int ih = h + 2 * i - 6;
        bool hv = (ih >= 0) && (ih < H_);
        #pragma unroll
        for (int j = 0; j < 7; ++j) {
            int iw = w + 2 * j - 6;
            bool v  = hv && (iw >= 0) && (iw < W_);
            float m = v ? 1.0f : 0.0f;
            int off = v ? (ih * W_ + iw) : 0;
            acc += (m * xb[off]) * ab[(size_t)(i * 7 + j) * HW_];
        }
    }
    out[idx] = acc;
}

// ===========================================================================
extern "C" void kernel_launch(void* const* d_in, const int* in_sizes, int n_in,
                              void* d_out, int out_size, void* d_ws, size_t ws_size,
                              hipStream_t stream)
{
    const float* x  = (const float*)d_in[0];
    const float* W1 = (const float*)d_in[1];
    const float* b1 = (const float*)d_in[2];
    const float* W2 = (const float*)d_in[3];
    const float* b2 = (const float*)d_in[4];
    float* out = (float*)d_out;

    // fast-path ws layout (bytes)
    const size_t xp_b    = (size_t)B_ * HP_ * HP_ * 256 * 2;        //  9,469,952
    const size_t wfb_b   = (size_t)NT * 8 * 4 * 64 * 8 * 2;         //  1,605,632
    const size_t kpart_b = (size_t)7 * M_TOT * NP * 4;              // 22,478,848
    const size_t attn_b  = (size_t)M_TOT * NT * 4;                  //  2,458,624
    const size_t cb_b    = 256;
    const size_t need = xp_b + wfb_b + kpart_b + attn_b + cb_b;     // ~36.0 MB

    if (ws_size >= need) {
        char* base = (char*)d_ws;
        __hip_bfloat16* xp  = (__hip_bfloat16*)base;
        __hip_bfloat16* wfb = (__hip_bfloat16*)(base + xp_b);
        float* kpart = (float*)(base + xp_b + wfb_b);
        float* attnP = (float*)(base + xp_b + wfb_b + kpart_b);
        float* cb    = (float*)(base + xp_b + wfb_b + kpart_b + attn_b);

        xpack2_kernel<<<2176, 256, 0, stream>>>(x, xp);
        wfuse_kernel <<<dim3(49, 8), 256, 0, stream>>>(W1, W2, wfb);
        cbias_kernel <<<1, 64, 0, stream>>>(W2, b1, b2, cb);
        conv1_mfma3  <<<728, 256, 0, stream>>>(xp, wfb, kpart);
        attn_fold    <<<3136, 256, 0, stream>>>(kpart, cb, attnP);
        out_kernel4  <<<3584, 256, 0, stream>>>(x, attnP, out);
    } else {
        // R1 fallback (~14.6 MB)
        float* wT   = (float*)d_ws;
        float* kbuf = wT + 1605632;
        float* attn = kbuf + 1605632;
        wt_kernel   <<<6272, 256, 0, stream>>>(W1, wT);
        conv1_kernel<<<dim3(14, 16, 4), 256, 0, stream>>>(x, wT, b1, kbuf);
        attn_kernel <<<3136, 256, 0, stream>>>(kbuf, W2, b2, attn);
        out_kernel  <<<12544, 256, 0, stream>>>(x, attn, out);
    }
}